// Round 8
// baseline (237.477 us; speedup 1.0000x reference)
//
#include <hip/hip_runtime.h>
#include <hip/hip_bf16.h>

#define N_NODES 50000
#define KNB 16
#define FDIM 128
#define HDIM 128
#define ALPHA 0.3f
#define BN_EPS 1e-3f
#define NATT 6250   // attn-role blocks (8 nodes each)
#define NOUT 391    // out-role blocks (128 rows each)

typedef __bf16 v8bf __attribute__((ext_vector_type(8)));
typedef float v4f __attribute__((ext_vector_type(4)));
typedef unsigned short ushort_t;

__device__ __forceinline__ float blo(unsigned int u) {
    union { float f; unsigned int i; } x; x.i = u << 16; return x.f;
}
__device__ __forceinline__ float bhi(unsigned int u) {
    union { float f; unsigned int i; } x; x.i = u & 0xffff0000u; return x.f;
}

__device__ __forceinline__ unsigned short f2bf(float f) {
    union { float f; unsigned int u; } x;
    x.f = f;
    unsigned int r = x.u + 0x7fffu + ((x.u >> 16) & 1u);  // RNE
    return (unsigned short)(r >> 16);
}

// packed f32x2 -> bf16x2 (RNE)
__device__ __forceinline__ unsigned int pk2(float a, float b) {
    __hip_bfloat162 h = __float22bfloat162_rn(make_float2(a, b));
    union { __hip_bfloat162 h; unsigned int u; } r; r.h = h; return r.u;
}

__device__ __forceinline__ float lrelu(float x) { return x > 0.f ? x : ALPHA * x; }

__device__ __forceinline__ v8bf load8f(const float* p) {
    float4 A = ((const float4*)p)[0];
    float4 B = ((const float4*)p)[1];
    union { v8bf v; unsigned int u[4]; } r;
    r.u[0] = pk2(A.x, A.y); r.u[1] = pk2(A.z, A.w);
    r.u[2] = pk2(B.x, B.y); r.u[3] = pk2(B.z, B.w);
    return r.v;
}

// ---- L2-bypass (agent-scope) helpers: XCD L2s are not coherent; producer
// (attn) stores pooled straight to L3, consumer (out) reads straight from L3.
__device__ __forceinline__ void st8_bypass(float* p, float a, float b) {
    union { float f[2]; unsigned long long u; } x;
    x.f[0] = a; x.f[1] = b;
    __hip_atomic_store((unsigned long long*)p, x.u, __ATOMIC_RELAXED,
                       __HIP_MEMORY_SCOPE_AGENT);
}
__device__ __forceinline__ v8bf load8f_bypass(const float* p) {
    union { unsigned long long u; float f[2]; } d0, d1, d2, d3;
    const unsigned long long* q = (const unsigned long long*)p;
    d0.u = __hip_atomic_load(q + 0, __ATOMIC_RELAXED, __HIP_MEMORY_SCOPE_AGENT);
    d1.u = __hip_atomic_load(q + 1, __ATOMIC_RELAXED, __HIP_MEMORY_SCOPE_AGENT);
    d2.u = __hip_atomic_load(q + 2, __ATOMIC_RELAXED, __HIP_MEMORY_SCOPE_AGENT);
    d3.u = __hip_atomic_load(q + 3, __ATOMIC_RELAXED, __HIP_MEMORY_SCOPE_AGENT);
    union { v8bf v; unsigned int u[4]; } r;
    r.u[0] = pk2(d0.f[0], d0.f[1]); r.u[1] = pk2(d1.f[0], d1.f[1]);
    r.u[2] = pk2(d2.f[0], d2.f[1]); r.u[3] = pk2(d3.f[0], d3.f[1]);
    return r.v;
}

// ---------------------------------------------------------------------------
// Kernel 0: convert + transpose weights to bf16 once; zero completion flags
// (stream order guarantees flags are 0 before the fused kernel runs).
// WT layout (ushort): [0) WqT 128x128 | [16384) WkT | [32768) WvT | [49152) W1T 128x256
// ---------------------------------------------------------------------------
__global__ __launch_bounds__(256) void prep_kernel(
    const float* __restrict__ Wq, const float* __restrict__ Wk,
    const float* __restrict__ Wv, const float* __restrict__ W1,
    ushort_t* __restrict__ WT, int* __restrict__ flags)
{
    const int idx = blockIdx.x * 256 + threadIdx.x;
    if (idx < 16384) {
        int k = idx >> 7, n = idx & 127;
        WT[n * 128 + k] = f2bf(Wq[idx]);
    } else if (idx < 32768) {
        int i = idx - 16384; int k = i >> 7, n = i & 127;
        WT[16384 + n * 128 + k] = f2bf(Wk[i]);
    } else if (idx < 49152) {
        int i = idx - 32768; int k = i >> 7, n = i & 127;
        WT[32768 + n * 128 + k] = f2bf(Wv[i]);
    } else if (idx < 81920) {
        int i = idx - 49152; int k = i >> 7, n = i & 127;  // k in [0,256)
        WT[49152 + n * 256 + k] = f2bf(W1[i]);
    } else if (idx < 81920 + NATT) {
        __hip_atomic_store(&flags[idx - 81920], 0, __ATOMIC_RELAXED,
                           __HIP_MEMORY_SCOPE_AGENT);
    }
}

// ---------------------------------------------------------------------------
// Kernel A (R2-EXACT — best measured): operand-swapped MFMA (D^T) +
// wave-private LDS staging + 1KB-linear dwordx4 copy-out. Single block does
// Q,K,V; B frags direct from L2-hot WT.
// ---------------------------------------------------------------------------
#define QSTRIDE 560   // bytes/row in Q staging tile (140 dwords: 2-way banks)
#define KVSTRIDE 528  // bytes/row in KV staging tile (132 dwords)
#define WTILE 18432   // per-wave LDS region (>= 32*560), 16B aligned

__global__ __launch_bounds__(256) void qkv_kernel(
    const float* __restrict__ E, const ushort_t* __restrict__ WT,
    const float* __restrict__ bq, const float* __restrict__ bk,
    const float* __restrict__ bv,
    float* __restrict__ Qo, ushort_t* __restrict__ KV)
{
    __shared__ char smem[4 * WTILE];

    const int tid  = threadIdx.x;
    const int wave = tid >> 6;
    const int lane = tid & 63;
    const int quad = lane >> 4;
    const int j    = lane & 15;
    const int row0 = blockIdx.x * 128 + wave * 32;

    char* const wbase = smem + wave * WTILE;

    const int ar0 = min(row0 + j,      N_NODES - 1);
    const int ar1 = min(row0 + 16 + j, N_NODES - 1);

    v8bf a0f[4], a1f[4];
#pragma unroll
    for (int ks = 0; ks < 4; ++ks) {
        const int k0 = ks * 32 + quad * 8;
        a0f[ks] = load8f(E + (size_t)ar0 * FDIM + k0);
        a1f[ks] = load8f(E + (size_t)ar1 * FDIM + k0);
    }

    const float* biases[3] = {bq, bk, bv};

    for (int w = 0; w < 3; ++w) {
        const ushort_t* __restrict__ Wsrc = WT + w * 16384;

        v4f acc[2][8];
#pragma unroll
        for (int rb = 0; rb < 2; ++rb)
#pragma unroll
            for (int c = 0; c < 8; ++c) acc[rb][c] = (v4f){0.f, 0.f, 0.f, 0.f};

#pragma unroll
        for (int ks = 0; ks < 4; ++ks) {
            const int k0 = ks * 32 + quad * 8;
            v8bf b[8];
#pragma unroll
            for (int c = 0; c < 8; ++c)
                b[c] = *(const v8bf*)(Wsrc + (c * 16 + j) * 128 + k0);
            // SWAPPED operands: D^T — lane (quad,j) holds rows row0+rb*16+j,
            // cols c*16+quad*4 .. +3 (4 consecutive columns).
#pragma unroll
            for (int c = 0; c < 8; ++c) {
                acc[0][c] = __builtin_amdgcn_mfma_f32_16x16x32_bf16(b[c], a0f[ks], acc[0][c], 0, 0, 0);
                acc[1][c] = __builtin_amdgcn_mfma_f32_16x16x32_bf16(b[c], a1f[ks], acc[1][c], 0, 0, 0);
            }
        }

        const float* __restrict__ bias = biases[w];

        if (w == 0) {
            // ---- Q: stage f32 tile (32 rows x 512B) then 1KB-linear stores
#pragma unroll
            for (int rb = 0; rb < 2; ++rb)
#pragma unroll
                for (int c = 0; c < 8; ++c) {
                    const float4 bb = ((const float4*)bias)[c * 4 + quad];
                    v4f v = acc[rb][c];
                    v[0] = lrelu(v[0] + bb.x); v[1] = lrelu(v[1] + bb.y);
                    v[2] = lrelu(v[2] + bb.z); v[3] = lrelu(v[3] + bb.w);
                    *(v4f*)(wbase + (rb * 16 + j) * QSTRIDE + (c * 16 + quad * 4) * 4) = v;
                }
#pragma unroll
            for (int t = 0; t < 16; ++t) {
                const int r  = 2 * t + (lane >> 5);
                const v4f v  = *(const v4f*)(wbase + r * QSTRIDE + (lane & 31) * 16);
                const int gr = row0 + r;
                if (gr < N_NODES)
                    *(v4f*)(Qo + (size_t)gr * HDIM + (lane & 31) * 4) = v;
            }
        } else {
            // ---- K (w=1) / V (w=2): pack bf16 into interleaved KV tile row
            const int voff = (w == 2) ? 256 : 0;  // V half at +256B in row
#pragma unroll
            for (int rb = 0; rb < 2; ++rb)
#pragma unroll
                for (int c = 0; c < 8; ++c) {
                    const float4 bb = ((const float4*)bias)[c * 4 + quad];
                    const v4f v = acc[rb][c];
                    uint2 u;
                    u.x = pk2(lrelu(v[0] + bb.x), lrelu(v[1] + bb.y));
                    u.y = pk2(lrelu(v[2] + bb.z), lrelu(v[3] + bb.w));
                    *(uint2*)(wbase + (rb * 16 + j) * KVSTRIDE + (c * 16 + quad * 4) * 2 + voff) = u;
                }
            if (w == 2) {
                // full 512B KV rows staged — 1KB-linear copy-out
#pragma unroll
                for (int t = 0; t < 16; ++t) {
                    const int r  = 2 * t + (lane >> 5);
                    const uint4 v = *(const uint4*)(wbase + r * KVSTRIDE + (lane & 31) * 16);
                    const int gr = row0 + r;
                    if (gr < N_NODES)   // guard: row 50000+ would smash WT in ws
                        *(uint4*)((char*)KV + (size_t)gr * 512 + (lane & 31) * 16) = v;
                }
            }
        }
    }
}

// ---------------------------------------------------------------------------
// Kernel B+C fused (R8): attn role (blocks [0,6250)) + out role ([6250,6641)).
// attn: R5-exact math; pooled stored via L2-BYPASS stores (straight to L3),
// vmcnt drain, then flag[bid]=1 (agent scope). out: E-half GEMM first (no
// dependency — overlaps with attn), then spins on its 16 flags, then the
// pooled-half GEMM via L2-BYPASS loads (reader XCD L2s hold stale q lines
// cached by attn-role q reads — bypass is mandatory). Deadlock-free by
// capacity: <=391 spinner blocks (1564 waves) vs 8192 wave slots, so attn
// blocks always schedule. Math bit-identical to R7 (absmax unchanged).
// ---------------------------------------------------------------------------
#define DOT8(qa, qb, kp) (qa.x*blo(kp.x) + qa.y*bhi(kp.x) + qa.z*blo(kp.y) + qa.w*bhi(kp.y) \
                        + qb.x*blo(kp.z) + qb.y*bhi(kp.z) + qb.z*blo(kp.w) + qb.w*bhi(kp.w))

__global__ __launch_bounds__(256) void attn_out_kernel(
    float* __restrict__ QP, const ushort_t* __restrict__ KV,
    const int* __restrict__ nbr,
    const float* __restrict__ E, const ushort_t* __restrict__ W1T,
    const float* __restrict__ b1,
    const float* __restrict__ gamma, const float* __restrict__ beta,
    const float* __restrict__ mmean, const float* __restrict__ mvar,
    int* __restrict__ flags)
{
    __shared__ ushort_t sW[128 * 136];

    const int tid  = threadIdx.x;
    const int wave = tid >> 6;
    const int lane = tid & 63;

    if (blockIdx.x < NATT) {
        // ================= attn role (R5-exact + bypass stores + flag) =====
        const int grp = lane >> 4;
        const int li  = lane & 15;
        const int n0 = __builtin_amdgcn_readfirstlane(blockIdx.x * 8 + wave * 2);
        const int n1 = n0 + 1;

        const float4* qr0 = (const float4*)(QP + (size_t)n0 * HDIM + li * 8);
        const float4 q0a = qr0[0], q0b = qr0[1];
        const float4* qr1 = (const float4*)(QP + (size_t)n1 * HDIM + li * 8);
        const float4 q1a = qr1[0], q1b = qr1[1];

        const int* nbA = nbr + n0 * KNB;
        const int* nbB = nbr + n1 * KNB;
        int nidA[4], nidB[4];
#pragma unroll
        for (int t = 0; t < 4; ++t) {
            int a0 = nbA[t*4+0]; a0 = ((unsigned)a0 < (unsigned)N_NODES) ? a0 : 0;
            int a1 = nbA[t*4+1]; a1 = ((unsigned)a1 < (unsigned)N_NODES) ? a1 : 0;
            int a2 = nbA[t*4+2]; a2 = ((unsigned)a2 < (unsigned)N_NODES) ? a2 : 0;
            int a3 = nbA[t*4+3]; a3 = ((unsigned)a3 < (unsigned)N_NODES) ? a3 : 0;
            int va = a0;
            va = (grp == 1) ? a1 : va;
            va = (grp == 2) ? a2 : va;
            va = (grp == 3) ? a3 : va;
            nidA[t] = va;
            int b0 = nbB[t*4+0]; b0 = ((unsigned)b0 < (unsigned)N_NODES) ? b0 : 0;
            int b1_ = nbB[t*4+1]; b1_ = ((unsigned)b1_ < (unsigned)N_NODES) ? b1_ : 0;
            int b2 = nbB[t*4+2]; b2 = ((unsigned)b2 < (unsigned)N_NODES) ? b2 : 0;
            int b3 = nbB[t*4+3]; b3 = ((unsigned)b3 < (unsigned)N_NODES) ? b3 : 0;
            int vb = b0;
            vb = (grp == 1) ? b1_ : vb;
            vb = (grp == 2) ? b2 : vb;
            vb = (grp == 3) ? b3 : vb;
            nidB[t] = vb;
        }

        const char* kvb = (const char*)KV;
        const size_t lo16 = (size_t)(li * 16);

        uint4 kA[4], kB[4], vA[4], vB[4];
#pragma unroll
        for (int t = 0; t < 4; ++t) {
            kA[t] = *(const uint4*)(kvb + (size_t)nidA[t] * 512 + lo16);
            kB[t] = *(const uint4*)(kvb + (size_t)nidB[t] * 512 + lo16);
            vA[t] = *(const uint4*)(kvb + (size_t)nidA[t] * 512 + 256 + lo16);
            vB[t] = *(const uint4*)(kvb + (size_t)nidB[t] * 512 + 256 + lo16);
        }

        float sA[4], sB[4];
#pragma unroll
        for (int t = 0; t < 4; ++t) {
            sA[t] = DOT8(q0a, q0b, kA[t]);
            sB[t] = DOT8(q1a, q1b, kB[t]);
        }
#pragma unroll
        for (int off = 1; off <= 8; off <<= 1) {
#pragma unroll
            for (int t = 0; t < 4; ++t) {
                sA[t] += __shfl_xor(sA[t], off, 64);
                sB[t] += __shfl_xor(sB[t], off, 64);
            }
        }

        float mA = fmaxf(fmaxf(sA[0], sA[1]), fmaxf(sA[2], sA[3]));
        float mB = fmaxf(fmaxf(sB[0], sB[1]), fmaxf(sB[2], sB[3]));
        mA = fmaxf(mA, __shfl_xor(mA, 16, 64)); mB = fmaxf(mB, __shfl_xor(mB, 16, 64));
        mA = fmaxf(mA, __shfl_xor(mA, 32, 64)); mB = fmaxf(mB, __shfl_xor(mB, 32, 64));
        float aA[4], aB[4];
#pragma unroll
        for (int t = 0; t < 4; ++t) {
            aA[t] = __expf(sA[t] - mA);
            aB[t] = __expf(sB[t] - mB);
        }
        float sumA = aA[0] + aA[1] + aA[2] + aA[3];
        float sumB = aB[0] + aB[1] + aB[2] + aB[3];
        sumA += __shfl_xor(sumA, 16, 64); sumB += __shfl_xor(sumB, 16, 64);
        sumA += __shfl_xor(sumA, 32, 64); sumB += __shfl_xor(sumB, 32, 64);
        const float invA = 1.f / sumA, invB = 1.f / sumB;
#pragma unroll
        for (int t = 0; t < 4; ++t) { aA[t] *= invA; aB[t] *= invB; }

        float pA[8] = {0,0,0,0,0,0,0,0}, pB[8] = {0,0,0,0,0,0,0,0};
#pragma unroll
        for (int t = 0; t < 4; ++t) {
            pA[0] += aA[t] * blo(vA[t].x); pA[1] += aA[t] * bhi(vA[t].x);
            pA[2] += aA[t] * blo(vA[t].y); pA[3] += aA[t] * bhi(vA[t].y);
            pA[4] += aA[t] * blo(vA[t].z); pA[5] += aA[t] * bhi(vA[t].z);
            pA[6] += aA[t] * blo(vA[t].w); pA[7] += aA[t] * bhi(vA[t].w);
            pB[0] += aB[t] * blo(vB[t].x); pB[1] += aB[t] * bhi(vB[t].x);
            pB[2] += aB[t] * blo(vB[t].y); pB[3] += aB[t] * bhi(vB[t].y);
            pB[4] += aB[t] * blo(vB[t].z); pB[5] += aB[t] * bhi(vB[t].z);
            pB[6] += aB[t] * blo(vB[t].w); pB[7] += aB[t] * bhi(vB[t].w);
        }
#pragma unroll
        for (int i = 0; i < 8; ++i) {
            pA[i] += __shfl_xor(pA[i], 16, 64); pB[i] += __shfl_xor(pB[i], 16, 64);
            pA[i] += __shfl_xor(pA[i], 32, 64); pB[i] += __shfl_xor(pB[i], 32, 64);
        }

        if (grp == 0) {
            float* o = QP + (size_t)n0 * HDIM + li * 8;
            st8_bypass(o + 0, pA[0], pA[1]); st8_bypass(o + 2, pA[2], pA[3]);
            st8_bypass(o + 4, pA[4], pA[5]); st8_bypass(o + 6, pA[6], pA[7]);
        } else if (grp == 1) {
            float* o = QP + (size_t)n1 * HDIM + li * 8;
            st8_bypass(o + 0, pB[0], pB[1]); st8_bypass(o + 2, pB[2], pB[3]);
            st8_bypass(o + 4, pB[4], pB[5]); st8_bypass(o + 6, pB[6], pB[7]);
        }
        asm volatile("s_waitcnt vmcnt(0)" ::: "memory");  // pooled at L3
        __syncthreads();                                  // all 4 waves done
        if (tid == 0)
            __hip_atomic_store(&flags[blockIdx.x], 1, __ATOMIC_RELAXED,
                               __HIP_MEMORY_SCOPE_AGENT);
        return;
    }

    // ================= out role (R2-exact + flag gate + bypass reads) ======
    const int bo   = blockIdx.x - NATT;
    const int quad = lane >> 4;
    const int j    = lane & 15;
    const int row0 = bo * 128 + wave * 32;

    const int ar0 = min(row0 + j,      N_NODES - 1);
    const int ar1 = min(row0 + 16 + j, N_NODES - 1);

    v4f acc[2][8];
#pragma unroll
    for (int rb = 0; rb < 2; ++rb)
#pragma unroll
        for (int c = 0; c < 8; ++c) acc[rb][c] = (v4f){0.f, 0.f, 0.f, 0.f};

    // ---- half 0: E @ W1_top (no dependency on attn — overlap work)
    for (int i = tid; i < 2048; i += 256) {
        int n = i >> 4, kc = i & 15;
        *(uint4*)(&sW[n * 136 + kc * 8]) = *(const uint4*)(W1T + n * 256 + kc * 8);
    }
    __syncthreads();
#pragma unroll
    for (int ks = 0; ks < 4; ++ks) {
        const int k0 = ks * 32 + quad * 8;
        v8bf a0 = load8f(E + (size_t)ar0 * 128 + k0);
        v8bf a1 = load8f(E + (size_t)ar1 * 128 + k0);
        v8bf b[8];
#pragma unroll
        for (int c = 0; c < 8; ++c)
            b[c] = *(const v8bf*)(&sW[(c * 16 + j) * 136 + k0]);
#pragma unroll
        for (int c = 0; c < 8; ++c) {
            acc[0][c] = __builtin_amdgcn_mfma_f32_16x16x32_bf16(a0, b[c], acc[0][c], 0, 0, 0);
            acc[1][c] = __builtin_amdgcn_mfma_f32_16x16x32_bf16(a1, b[c], acc[1][c], 0, 0, 0);
        }
    }
    __syncthreads();

    // ---- half 1 staging + flag gate
    for (int i = tid; i < 2048; i += 256) {
        int n = i >> 4, kc = i & 15;
        *(uint4*)(&sW[n * 136 + kc * 8]) =
            *(const uint4*)(W1T + n * 256 + 128 + kc * 8);
    }
    if (tid < 16) {
        int f = 16 * bo + tid;
        if (f >= NATT) f = NATT - 1;   // tail block's clamped rows
        while (__hip_atomic_load(&flags[f], __ATOMIC_RELAXED,
                                 __HIP_MEMORY_SCOPE_AGENT) == 0)
            __builtin_amdgcn_s_sleep(2);
    }
    __syncthreads();   // covers staging + flag observation for all waves

    // ---- half 1: pooled @ W1_bot via L3-bypass loads
#pragma unroll
    for (int ks = 0; ks < 4; ++ks) {
        const int k0 = ks * 32 + quad * 8;
        v8bf a0 = load8f_bypass(QP + (size_t)ar0 * 128 + k0);
        v8bf a1 = load8f_bypass(QP + (size_t)ar1 * 128 + k0);
        v8bf b[8];
#pragma unroll
        for (int c = 0; c < 8; ++c)
            b[c] = *(const v8bf*)(&sW[(c * 16 + j) * 136 + k0]);
#pragma unroll
        for (int c = 0; c < 8; ++c) {
            acc[0][c] = __builtin_amdgcn_mfma_f32_16x16x32_bf16(a0, b[c], acc[0][c], 0, 0, 0);
            acc[1][c] = __builtin_amdgcn_mfma_f32_16x16x32_bf16(a1, b[c], acc[1][c], 0, 0, 0);
        }
    }
    __syncthreads();   // all pooled reads complete before epilogue writes

    float scale_[8], shift_[8], bias_[8];
#pragma unroll
    for (int c = 0; c < 8; ++c) {
        const int col = c * 16 + j;
        const float sc = gamma[col] * rsqrtf(mvar[col] + BN_EPS);
        scale_[c] = sc;
        shift_[c] = beta[col] - mmean[col] * sc;
        bias_[c]  = b1[col];
    }

#pragma unroll
    for (int rb = 0; rb < 2; ++rb)
#pragma unroll
        for (int c = 0; c < 8; ++c)
#pragma unroll
            for (int i = 0; i < 4; ++i)
                acc[rb][c][i] = lrelu(acc[rb][c][i] + bias_[c]);

#pragma unroll
    for (int rb = 0; rb < 2; ++rb) {
#pragma unroll
        for (int i = 0; i < 4; ++i) {
            float ss = 0.f;
#pragma unroll
            for (int c = 0; c < 8; ++c) ss += acc[rb][c][i] * acc[rb][c][i];
            ss += __shfl_xor(ss, 1, 64);
            ss += __shfl_xor(ss, 2, 64);
            ss += __shfl_xor(ss, 4, 64);
            ss += __shfl_xor(ss, 8, 64);
            const float invn = 1.f / (sqrtf(ss) + 1e-6f);
            const int r = row0 + rb * 16 + quad * 4 + i;
            if (r < N_NODES) {
#pragma unroll
                for (int c = 0; c < 8; ++c)
                    QP[(size_t)r * HDIM + c * 16 + j] =
                        acc[rb][c][i] * invn * scale_[c] + shift_[c];
            }
        }
    }
}

extern "C" void kernel_launch(void* const* d_in, const int* in_sizes, int n_in,
                              void* d_out, int out_size, void* d_ws, size_t ws_size,
                              hipStream_t stream)
{
    const float* E     = (const float*)d_in[0];
    const int*   nbr   = (const int*)d_in[2];
    const float* Wq    = (const float*)d_in[3];
    const float* bq    = (const float*)d_in[4];
    const float* Wk    = (const float*)d_in[5];
    const float* bk    = (const float*)d_in[6];
    const float* Wv    = (const float*)d_in[7];
    const float* bv    = (const float*)d_in[8];
    const float* W1    = (const float*)d_in[9];
    const float* b1    = (const float*)d_in[10];
    const float* gam   = (const float*)d_in[11];
    const float* bet   = (const float*)d_in[12];
    const float* mmean = (const float*)d_in[13];
    const float* mvar  = (const float*)d_in[14];

    // ws: KV bf16 25.6 MB | WT bf16 160 KB | flags 25 KB  = 25.79 MB total
    // (within the PROVEN 25.76+ε budget; R7's 38.56 MB overflowed d_ws).
    // Q (f32) then pooled (f32) then final output share d_out.
    ushort_t* KV    = (ushort_t*)d_ws;
    ushort_t* WT    = KV + (size_t)N_NODES * 256;
    int*      flags = (int*)(WT + 81920);
    float* QP = (float*)d_out;

    prep_kernel<<<345, 256, 0, stream>>>(Wq, Wk, Wv, W1, WT, flags);
    qkv_kernel<<<(N_NODES + 127) / 128, 256, 0, stream>>>(E, WT, bq, bk, bv, QP, KV);
    attn_out_kernel<<<NATT + NOUT, 256, 0, stream>>>(
        QP, KV, nbr, E, WT + 49152, b1, gam, bet, mmean, mvar, flags);
}

// Round 9
// 209.425 us; speedup vs baseline: 1.1339x; 1.1339x over previous
//
#include <hip/hip_runtime.h>
#include <hip/hip_bf16.h>

#define N_NODES 50000
#define KNB 16
#define FDIM 128
#define HDIM 128
#define ALPHA 0.3f
#define BN_EPS 1e-3f

typedef __bf16 v8bf __attribute__((ext_vector_type(8)));
typedef float v4f __attribute__((ext_vector_type(4)));
typedef unsigned short ushort_t;

__device__ __forceinline__ float blo(unsigned int u) {
    union { float f; unsigned int i; } x; x.i = u << 16; return x.f;
}
__device__ __forceinline__ float bhi(unsigned int u) {
    union { float f; unsigned int i; } x; x.i = u & 0xffff0000u; return x.f;
}

__device__ __forceinline__ unsigned short f2bf(float f) {
    union { float f; unsigned int u; } x;
    x.f = f;
    unsigned int r = x.u + 0x7fffu + ((x.u >> 16) & 1u);  // RNE
    return (unsigned short)(r >> 16);
}

// packed f32x2 -> bf16x2 (RNE)
__device__ __forceinline__ unsigned int pk2(float a, float b) {
    __hip_bfloat162 h = __float22bfloat162_rn(make_float2(a, b));
    union { __hip_bfloat162 h; unsigned int u; } r; r.h = h; return r.u;
}

__device__ __forceinline__ float lrelu(float x) { return x > 0.f ? x : ALPHA * x; }

__device__ __forceinline__ v8bf load8f(const float* p) {
    float4 A = ((const float4*)p)[0];
    float4 B = ((const float4*)p)[1];
    union { v8bf v; unsigned int u[4]; } r;
    r.u[0] = pk2(A.x, A.y); r.u[1] = pk2(A.z, A.w);
    r.u[2] = pk2(B.x, B.y); r.u[3] = pk2(B.z, B.w);
    return r.v;
}

// ---------------------------------------------------------------------------
// Kernel 0: convert + transpose weights to bf16 once.
// WT layout (ushort): [0) WqT 128x128 | [16384) WkT | [32768) WvT | [49152) W1T 128x256
// ---------------------------------------------------------------------------
__global__ __launch_bounds__(256) void prep_kernel(
    const float* __restrict__ Wq, const float* __restrict__ Wk,
    const float* __restrict__ Wv, const float* __restrict__ W1,
    ushort_t* __restrict__ WT)
{
    const int idx = blockIdx.x * 256 + threadIdx.x;
    if (idx < 16384) {
        int k = idx >> 7, n = idx & 127;
        WT[n * 128 + k] = f2bf(Wq[idx]);
    } else if (idx < 32768) {
        int i = idx - 16384; int k = i >> 7, n = i & 127;
        WT[16384 + n * 128 + k] = f2bf(Wk[i]);
    } else if (idx < 49152) {
        int i = idx - 32768; int k = i >> 7, n = i & 127;
        WT[32768 + n * 128 + k] = f2bf(Wv[i]);
    } else if (idx < 81920) {
        int i = idx - 49152; int k = i >> 7, n = i & 127;  // k in [0,256)
        WT[49152 + n * 256 + k] = f2bf(W1[i]);
    }
}

// ---------------------------------------------------------------------------
// Kernel A (R2-EXACT — best measured total, 210.1 µs):
// operand-swapped MFMA (D^T) + wave-private LDS staging + 1KB-linear
// dwordx4 copy-out. Single block does Q,K,V; B frags direct from L2-hot WT.
// ---------------------------------------------------------------------------
#define QSTRIDE 560   // bytes/row in Q staging tile (140 dwords: 2-way banks)
#define KVSTRIDE 528  // bytes/row in KV staging tile (132 dwords)
#define WTILE 18432   // per-wave LDS region (>= 32*560), 16B aligned

__global__ __launch_bounds__(256) void qkv_kernel(
    const float* __restrict__ E, const ushort_t* __restrict__ WT,
    const float* __restrict__ bq, const float* __restrict__ bk,
    const float* __restrict__ bv,
    float* __restrict__ Qo, ushort_t* __restrict__ KV)
{
    __shared__ char smem[4 * WTILE];

    const int tid  = threadIdx.x;
    const int wave = tid >> 6;
    const int lane = tid & 63;
    const int quad = lane >> 4;
    const int j    = lane & 15;
    const int row0 = blockIdx.x * 128 + wave * 32;

    char* const wbase = smem + wave * WTILE;

    const int ar0 = min(row0 + j,      N_NODES - 1);
    const int ar1 = min(row0 + 16 + j, N_NODES - 1);

    v8bf a0f[4], a1f[4];
#pragma unroll
    for (int ks = 0; ks < 4; ++ks) {
        const int k0 = ks * 32 + quad * 8;
        a0f[ks] = load8f(E + (size_t)ar0 * FDIM + k0);
        a1f[ks] = load8f(E + (size_t)ar1 * FDIM + k0);
    }

    const float* biases[3] = {bq, bk, bv};

    for (int w = 0; w < 3; ++w) {
        const ushort_t* __restrict__ Wsrc = WT + w * 16384;

        v4f acc[2][8];
#pragma unroll
        for (int rb = 0; rb < 2; ++rb)
#pragma unroll
            for (int c = 0; c < 8; ++c) acc[rb][c] = (v4f){0.f, 0.f, 0.f, 0.f};

#pragma unroll
        for (int ks = 0; ks < 4; ++ks) {
            const int k0 = ks * 32 + quad * 8;
            v8bf b[8];
#pragma unroll
            for (int c = 0; c < 8; ++c)
                b[c] = *(const v8bf*)(Wsrc + (c * 16 + j) * 128 + k0);
            // SWAPPED operands: D^T — lane (quad,j) holds rows row0+rb*16+j,
            // cols c*16+quad*4 .. +3 (4 consecutive columns).
#pragma unroll
            for (int c = 0; c < 8; ++c) {
                acc[0][c] = __builtin_amdgcn_mfma_f32_16x16x32_bf16(b[c], a0f[ks], acc[0][c], 0, 0, 0);
                acc[1][c] = __builtin_amdgcn_mfma_f32_16x16x32_bf16(b[c], a1f[ks], acc[1][c], 0, 0, 0);
            }
        }

        const float* __restrict__ bias = biases[w];

        if (w == 0) {
            // ---- Q: stage f32 tile (32 rows x 512B) then 1KB-linear stores
#pragma unroll
            for (int rb = 0; rb < 2; ++rb)
#pragma unroll
                for (int c = 0; c < 8; ++c) {
                    const float4 bb = ((const float4*)bias)[c * 4 + quad];
                    v4f v = acc[rb][c];
                    v[0] = lrelu(v[0] + bb.x); v[1] = lrelu(v[1] + bb.y);
                    v[2] = lrelu(v[2] + bb.z); v[3] = lrelu(v[3] + bb.w);
                    *(v4f*)(wbase + (rb * 16 + j) * QSTRIDE + (c * 16 + quad * 4) * 4) = v;
                }
#pragma unroll
            for (int t = 0; t < 16; ++t) {
                const int r  = 2 * t + (lane >> 5);
                const v4f v  = *(const v4f*)(wbase + r * QSTRIDE + (lane & 31) * 16);
                const int gr = row0 + r;
                if (gr < N_NODES)
                    *(v4f*)(Qo + (size_t)gr * HDIM + (lane & 31) * 4) = v;
            }
        } else {
            // ---- K (w=1) / V (w=2): pack bf16 into interleaved KV tile row
            const int voff = (w == 2) ? 256 : 0;  // V half at +256B in row
#pragma unroll
            for (int rb = 0; rb < 2; ++rb)
#pragma unroll
                for (int c = 0; c < 8; ++c) {
                    const float4 bb = ((const float4*)bias)[c * 4 + quad];
                    const v4f v = acc[rb][c];
                    uint2 u;
                    u.x = pk2(lrelu(v[0] + bb.x), lrelu(v[1] + bb.y));
                    u.y = pk2(lrelu(v[2] + bb.z), lrelu(v[3] + bb.w));
                    *(uint2*)(wbase + (rb * 16 + j) * KVSTRIDE + (c * 16 + quad * 4) * 2 + voff) = u;
                }
            if (w == 2) {
                // full 512B KV rows staged — 1KB-linear copy-out
#pragma unroll
                for (int t = 0; t < 16; ++t) {
                    const int r  = 2 * t + (lane >> 5);
                    const uint4 v = *(const uint4*)(wbase + r * KVSTRIDE + (lane & 31) * 16);
                    const int gr = row0 + r;
                    if (gr < N_NODES)   // guard: row 50000+ would smash WT in ws
                        *(uint4*)((char*)KV + (size_t)gr * 512 + (lane & 31) * 16) = v;
                }
            }
        }
    }
}

// ---------------------------------------------------------------------------
// Kernel B (R2-EXACT): one wave per node, 4 nodes/block, 12500 blocks.
// Reads q (f32) from QP[node], overwrites the same row with pooled (f32) —
// same-wave read-before-write, safe. No LDS, no barriers.
// Pinned by per-XCD compulsory L2 fill (FETCH 188 MB = 8 XCD x ~23.5 MB)
// at the ~3.7 TB/s fill ceiling — schedule-invariant (R2/R3/R5/R8 agree).
// ---------------------------------------------------------------------------
__global__ __launch_bounds__(256) void attn_kernel(
    float* __restrict__ QP, const ushort_t* __restrict__ KV,
    const int* __restrict__ nbr)
{
    const int tid  = threadIdx.x;
    const int wave = tid >> 6;
    const int lane = tid & 63;
    const int node = __builtin_amdgcn_readfirstlane(blockIdx.x * 4 + wave);

    const float2 qp = ((const float2*)(QP + (size_t)node * HDIM))[lane];

    int idxs[KNB];
    const int* nb = nbr + node * KNB;   // uniform base -> scalar loads
#pragma unroll
    for (int t = 0; t < KNB; ++t) {
        int id = nb[t];
        idxs[t] = ((unsigned)id < (unsigned)N_NODES) ? id : 0;
    }

    float sc[KNB];
#pragma unroll
    for (int t = 0; t < KNB; ++t) {
        const unsigned int kp = ((const unsigned int*)(KV + (size_t)idxs[t] * 256))[lane];
        float p = qp.x * blo(kp) + qp.y * bhi(kp);
#pragma unroll
        for (int off = 32; off >= 1; off >>= 1) p += __shfl_xor(p, off, 64);
        sc[t] = p;
    }

    float m = sc[0];
#pragma unroll
    for (int t = 1; t < KNB; ++t) m = fmaxf(m, sc[t]);
    float s = 0.f;
#pragma unroll
    for (int t = 0; t < KNB; ++t) { sc[t] = __expf(sc[t] - m); s += sc[t]; }
    const float inv = 1.f / s;

    float p0 = 0.f, p1 = 0.f;
#pragma unroll
    for (int t = 0; t < KNB; ++t) {
        const unsigned int vp = ((const unsigned int*)(KV + (size_t)idxs[t] * 256 + 128))[lane];
        const float a = sc[t] * inv;
        p0 += a * blo(vp);
        p1 += a * bhi(vp);
    }

    ((float2*)(QP + (size_t)node * HDIM))[lane] = make_float2(p0, p1);
}

// ---------------------------------------------------------------------------
// Kernel C (R2-EXACT, R0-style — best-in-total measured):
// out = BN(rownorm(lrelu([E,pooled]@W1+b1))). pooled (f32) lives in d_out;
// result overwrites d_out. The barrier at the end of half=1 orders all
// pooled reads before any epilogue write within a block; blocks read/write
// only their own row range — no cross-block hazard.
// ---------------------------------------------------------------------------
__global__ __launch_bounds__(256) void out_kernel(
    const float* __restrict__ E, const ushort_t* __restrict__ W1T,
    const float* __restrict__ b1,
    const float* __restrict__ gamma, const float* __restrict__ beta,
    const float* __restrict__ mmean, const float* __restrict__ mvar,
    float* __restrict__ OutP)   // pooled (in) + out (result)
{
    __shared__ ushort_t sW[128 * 136];

    const int tid  = threadIdx.x;
    const int wave = tid >> 6;
    const int lane = tid & 63;
    const int quad = lane >> 4;
    const int j    = lane & 15;
    const int row0 = blockIdx.x * 128 + wave * 32;

    const int ar0 = min(row0 + j,      N_NODES - 1);
    const int ar1 = min(row0 + 16 + j, N_NODES - 1);

    v4f acc[2][8];
#pragma unroll
    for (int rb = 0; rb < 2; ++rb)
#pragma unroll
        for (int c = 0; c < 8; ++c) acc[rb][c] = (v4f){0.f, 0.f, 0.f, 0.f};

    for (int half = 0; half < 2; ++half) {
        for (int i = tid; i < 2048; i += 256) {
            int n = i >> 4, kc = i & 15;
            *(uint4*)(&sW[n * 136 + kc * 8]) =
                *(const uint4*)(W1T + n * 256 + half * 128 + kc * 8);
        }
        __syncthreads();

        const float* Abase = (half == 0) ? E : (const float*)OutP;
#pragma unroll
        for (int ks = 0; ks < 4; ++ks) {
            const int k0 = ks * 32 + quad * 8;
            v8bf a0 = load8f(Abase + (size_t)ar0 * 128 + k0);
            v8bf a1 = load8f(Abase + (size_t)ar1 * 128 + k0);
            v8bf b[8];
#pragma unroll
            for (int c = 0; c < 8; ++c)
                b[c] = *(const v8bf*)(&sW[(c * 16 + j) * 136 + k0]);
#pragma unroll
            for (int c = 0; c < 8; ++c) {
                acc[0][c] = __builtin_amdgcn_mfma_f32_16x16x32_bf16(a0, b[c], acc[0][c], 0, 0, 0);
                acc[1][c] = __builtin_amdgcn_mfma_f32_16x16x32_bf16(a1, b[c], acc[1][c], 0, 0, 0);
            }
        }
        __syncthreads();   // orders pooled reads before epilogue writes
    }

    float scale_[8], shift_[8], bias_[8];
#pragma unroll
    for (int c = 0; c < 8; ++c) {
        const int col = c * 16 + j;
        const float sc = gamma[col] * rsqrtf(mvar[col] + BN_EPS);
        scale_[c] = sc;
        shift_[c] = beta[col] - mmean[col] * sc;
        bias_[c]  = b1[col];
    }

#pragma unroll
    for (int rb = 0; rb < 2; ++rb)
#pragma unroll
        for (int c = 0; c < 8; ++c)
#pragma unroll
            for (int i = 0; i < 4; ++i)
                acc[rb][c][i] = lrelu(acc[rb][c][i] + bias_[c]);

#pragma unroll
    for (int rb = 0; rb < 2; ++rb) {
#pragma unroll
        for (int i = 0; i < 4; ++i) {
            float ss = 0.f;
#pragma unroll
            for (int c = 0; c < 8; ++c) ss += acc[rb][c][i] * acc[rb][c][i];
            ss += __shfl_xor(ss, 1, 64);
            ss += __shfl_xor(ss, 2, 64);
            ss += __shfl_xor(ss, 4, 64);
            ss += __shfl_xor(ss, 8, 64);
            const float invn = 1.f / (sqrtf(ss) + 1e-6f);
            const int r = row0 + rb * 16 + quad * 4 + i;
            if (r < N_NODES) {
#pragma unroll
                for (int c = 0; c < 8; ++c)
                    OutP[(size_t)r * HDIM + c * 16 + j] =
                        acc[rb][c][i] * invn * scale_[c] + shift_[c];
            }
        }
    }
}

extern "C" void kernel_launch(void* const* d_in, const int* in_sizes, int n_in,
                              void* d_out, int out_size, void* d_ws, size_t ws_size,
                              hipStream_t stream)
{
    const float* E     = (const float*)d_in[0];
    const int*   nbr   = (const int*)d_in[2];
    const float* Wq    = (const float*)d_in[3];
    const float* bq    = (const float*)d_in[4];
    const float* Wk    = (const float*)d_in[5];
    const float* bk    = (const float*)d_in[6];
    const float* Wv    = (const float*)d_in[7];
    const float* bv    = (const float*)d_in[8];
    const float* W1    = (const float*)d_in[9];
    const float* b1    = (const float*)d_in[10];
    const float* gam   = (const float*)d_in[11];
    const float* bet   = (const float*)d_in[12];
    const float* mmean = (const float*)d_in[13];
    const float* mvar  = (const float*)d_in[14];

    // ws: KV interleaved bf16 (25.6 MB) + WT bf16 (160 KB) = 25.76 MB total
    // (PROVEN budget). Q (f32) then pooled (f32) share d_out.
    ushort_t* KV = (ushort_t*)d_ws;
    ushort_t* WT = KV + (size_t)N_NODES * 256;
    float* QP = (float*)d_out;

    const int gridA = (N_NODES + 127) / 128;  // 391
    prep_kernel<<<320, 256, 0, stream>>>(Wq, Wk, Wv, W1, WT);
    qkv_kernel<<<gridA, 256, 0, stream>>>(E, WT, bq, bk, bv, QP, KV);
    attn_kernel<<<N_NODES / 4, 256, 0, stream>>>(QP, KV, nbr);
    out_kernel<<<gridA, 256, 0, stream>>>(E, WT + 49152, b1, gam, bet, mmean, mvar, QP);
}